// Round 3
// baseline (321.467 us; speedup 1.0000x reference)
//
#include <hip/hip_runtime.h>

// NetVLAD — bf16 MFMA, register-resident weights (round 3).
// B=32, N=4096, D=256, K=128, Dc=64.
// Phase1: 512 blocks (16/batch, 256 rows each), 256 thr (4 waves), 2 blk/CU.
//   Weights live in per-wave persistent VGPR B-fragments (loaded once, global).
//   Each wave owns 3 of 12 col-tiles (8 Wa + 4 W1) across all 4 row-tiles of a
//   64-row iter. LDS only for: XF (staged X frags), AT (assign^T A-frags),
//   SF (sq B-frags), HF (h A-frags), softmax sums. 3 barriers/iter.
//   Per-block partial agg/mass stored plain (no atomics); phase2 reduces.
// MFMA 16x16x32 layouts (m89/m120-verified):
//   A: lane holds A[m=lane&15][k=(lane>>4)*8+j]
//   B: lane holds B[k=(lane>>4)*8+j][n=lane&15]
//   C/D: lane holds D[row=(lane>>4)*4+reg][col=lane&15]

#define B_   32
#define N_   4096
#define D_   256
#define K_   128
#define DC_  64
#define ITERS 4           // 64-row iters per block (256 rows)
#define BLKPB 16
#define NEG  0.01f

typedef __attribute__((ext_vector_type(8))) short bf16x8;
typedef __attribute__((ext_vector_type(4))) float f32x4;

// LDS byte offsets (dynamic LDS, total 66304 B -> 2 blocks/CU)
#define XF_OFF   0        // 4rt x 8ks x 64 lanes x 16B = 32768
#define AT_OFF   32768    // 8mt x 2ks x 64 x 16 = 16384
#define SF_OFF   49152    // 4nt x 2ks x 64 x 16 = 8192
#define HF_OFF   57344    // 4rt x 2ksE x 64 x 16 = 8192
#define SSUM_OFF 65536    // float[3][64] = 768
#define LDS_BYTES 66304

__device__ __forceinline__ unsigned short f2bf(float x) {
  union { float f; unsigned u; } v; v.f = x;
  unsigned r = v.u + 0x7fffu + ((v.u >> 16) & 1u);
  return (unsigned short)(r >> 16);
}
__device__ __forceinline__ unsigned pack2(float a, float b) {
  return (unsigned)f2bf(a) | ((unsigned)f2bf(b) << 16);
}
__device__ __forceinline__ bf16x8 pack8(float4 a, float4 c) {
  union { uint4 u; bf16x8 v; } z;
  z.u.x = pack2(a.x, a.y); z.u.y = pack2(a.z, a.w);
  z.u.z = pack2(c.x, c.y); z.u.w = pack2(c.z, c.w);
  return z.v;
}
__device__ __forceinline__ bf16x8 ldf(const char* s, int off) {
  return *reinterpret_cast<const bf16x8*>(s + off);
}

__global__ __launch_bounds__(256, 2)
void netvlad_phase1(const float* __restrict__ desc, const float* __restrict__ W1,
                    const float* __restrict__ b1, const float* __restrict__ W2,
                    const float* __restrict__ b2, const float* __restrict__ Wa,
                    const float* __restrict__ ba,
                    float* __restrict__ aggP, float* __restrict__ massP, int mode)
{
  extern __shared__ char smem[];
  const int t    = threadIdx.x;
  const int b    = blockIdx.x >> 4;
  const int blk  = blockIdx.x & 15;
  const int w    = t >> 6;
  const int lane = t & 63;
  const int li   = lane & 15;
  const int quad = lane >> 4;
  const int nWa  = (w == 3) ? 0 : (w == 2 ? 2 : 3);   // wave-uniform

  // ---- persistent B fragments: 3 col-tiles (Wa k-tiles / W1 e-tiles) ----
  bf16x8 b12[3][8];
  #pragma unroll
  for (int j = 0; j < 3; ++j) {
    const int ct = 3 * w + j;
    const float* base = (ct < 8) ? (Wa + (size_t)(ct * 16 + li) * D_)
                                 : (W1 + (size_t)((ct - 8) * 16 + li) * D_);
    #pragma unroll
    for (int ks = 0; ks < 8; ++ks) {
      const float* s = base + ks * 32 + quad * 8;
      b12[j][ks] = pack8(*(const float4*)s, *(const float4*)(s + 4));
    }
  }
  bf16x8 w2b[2];
  #pragma unroll
  for (int ks = 0; ks < 2; ++ks) {
    const float* s = W2 + (size_t)(w * 16 + li) * DC_ + ks * 32 + quad * 8;
    w2b[ks] = pack8(*(const float4*)s, *(const float4*)(s + 4));
  }
  float bias12[3];
  #pragma unroll
  for (int j = 0; j < 3; ++j) {
    const int ct = 3 * w + j;
    bias12[j] = (ct < 8) ? ba[ct * 16 + li] : b1[(ct - 8) * 16 + li];
  }
  const float b2r = b2[w * 16 + li];

  // ---- X staging: 2 chunks of 4 frag-slots per thread ----
  float4 xp[8];
  auto issueX = [&](int it, int c) {
    const int n0 = blk * 256 + it * 64;
    #pragma unroll
    for (int i = 0; i < 4; ++i) {
      const int s  = t + (c * 4 + i) * 256;
      const int rt = s >> 9, ks = (s >> 6) & 7, L = s & 63;
      const float* src = desc + (size_t)(b * N_ + n0 + rt * 16 + (L & 15)) * D_
                       + ks * 32 + ((L >> 4) << 3);
      xp[2 * i]     = *(const float4*)src;
      xp[2 * i + 1] = *(const float4*)(src + 4);
    }
  };
  auto storeX = [&](int c) {
    #pragma unroll
    for (int i = 0; i < 4; ++i) {
      const int s = t + (c * 4 + i) * 256;
      union { uint4 u; } z;
      z.u.x = pack2(xp[2 * i].x,     xp[2 * i].y);
      z.u.y = pack2(xp[2 * i].z,     xp[2 * i].w);
      z.u.z = pack2(xp[2 * i + 1].x, xp[2 * i + 1].y);
      z.u.w = pack2(xp[2 * i + 1].z, xp[2 * i + 1].w);
      *reinterpret_cast<uint4*>(smem + XF_OFF + s * 16) = z.u;
    }
  };

  f32x4 gacc[2][4];
  #pragma unroll
  for (int m = 0; m < 2; ++m)
    #pragma unroll
    for (int nt = 0; nt < 4; ++nt) gacc[m][nt] = (f32x4){0.f, 0.f, 0.f, 0.f};
  float massA[3] = {0.f, 0.f, 0.f};

  issueX(0, 0); storeX(0); issueX(0, 1); storeX(1);
  __syncthreads();

  for (int it = 0; it < ITERS; ++it) {
    // ---- GEMM1/2: 4 rt x 3 ct x 8 ks MFMAs, A from LDS, B from regs ----
    f32x4 accT[4][3];
    #pragma unroll
    for (int rt = 0; rt < 4; ++rt)
      #pragma unroll
      for (int j = 0; j < 3; ++j)
        accT[rt][j] = (f32x4){bias12[j], bias12[j], bias12[j], bias12[j]};
    #pragma unroll
    for (int rt = 0; rt < 4; ++rt) {
      #pragma unroll
      for (int ks = 0; ks < 8; ++ks) {
        bf16x8 xa = ldf(smem, XF_OFF + ((rt * 8 + ks) * 64 + lane) * 16);
        #pragma unroll
        for (int j = 0; j < 3; ++j)
          accT[rt][j] = __builtin_amdgcn_mfma_f32_16x16x32_bf16(xa, b12[j][ks], accT[rt][j], 0, 0, 0);
      }
    }

    // ---- exp + partial row-sums (no max pass: |logit| < ~6) ----
    if (w < 3) {
      #pragma unroll
      for (int rt = 0; rt < 4; ++rt) {
        float ps[4];
        #pragma unroll
        for (int r = 0; r < 4; ++r) {
          float s = 0.f;
          #pragma unroll
          for (int j = 0; j < 3; ++j) if (j < nWa) {
            float e = __expf(accT[rt][j][r]);
            accT[rt][j][r] = e;
            s += e;
          }
          #pragma unroll
          for (int off = 1; off < 16; off <<= 1) s += __shfl_xor(s, off, 64);
          ps[r] = s;
        }
        if (li == 0)
          *reinterpret_cast<float4*>(smem + SSUM_OFF + (w * 64 + rt * 16 + quad * 4) * 4)
            = make_float4(ps[0], ps[1], ps[2], ps[3]);
      }
    }
    if (it + 1 < ITERS) issueX(it + 1, 0);
    __syncthreads();   // B1: sums ready; XF(it) dead

    if (it + 1 < ITERS) { storeX(0); issueX(it + 1, 1); }

    // ---- normalize -> AT frags; leaky -> HF frags ----
    if (w < 3) {
      float4 inv4[4];
      #pragma unroll
      for (int rt = 0; rt < 4; ++rt) {
        float4 s0 = *reinterpret_cast<float4*>(smem + SSUM_OFF + (0 * 64 + rt * 16 + quad * 4) * 4);
        float4 s1 = *reinterpret_cast<float4*>(smem + SSUM_OFF + (1 * 64 + rt * 16 + quad * 4) * 4);
        float4 s2 = *reinterpret_cast<float4*>(smem + SSUM_OFF + (2 * 64 + rt * 16 + quad * 4) * 4);
        inv4[rt].x = 1.f / (s0.x + s1.x + s2.x);
        inv4[rt].y = 1.f / (s0.y + s1.y + s2.y);
        inv4[rt].z = 1.f / (s0.z + s1.z + s2.z);
        inv4[rt].w = 1.f / (s0.w + s1.w + s2.w);
      }
      #pragma unroll
      for (int j = 0; j < 3; ++j) if (j < nWa) {
        const int ct = 3 * w + j;
        #pragma unroll
        for (int rt = 0; rt < 4; ++rt) {
          float a0 = accT[rt][j][0] * inv4[rt].x;
          float a1 = accT[rt][j][1] * inv4[rt].y;
          float a2 = accT[rt][j][2] * inv4[rt].z;
          float a3 = accT[rt][j][3] * inv4[rt].w;
          massA[j] += a0 + a1 + a2 + a3;
          uint2 pk; pk.x = pack2(a0, a1); pk.y = pack2(a2, a3);
          const int laneA = li + 16 * ((rt & 1) * 2 + (quad >> 1));
          *reinterpret_cast<uint2*>(smem + AT_OFF
              + ((ct * 2 + (rt >> 1)) * 64 + laneA) * 16 + (quad & 1) * 8) = pk;
        }
      }
    }
    #pragma unroll
    for (int j = 0; j < 3; ++j) if (j >= nWa) {
      const int et  = 3 * w + j - 8;
      const int ksE = et >> 1;
      const int lhb = 16 * ((et & 1) * 2 + (li >> 3));
      #pragma unroll
      for (int rt = 0; rt < 4; ++rt) {
        #pragma unroll
        for (int r = 0; r < 4; ++r) {
          float h = accT[rt][j][r];
          h = h >= 0.f ? h : NEG * h;
          *reinterpret_cast<unsigned short*>(smem + HF_OFF
              + ((rt * 2 + ksE) * 64 + (quad * 4 + r) + lhb) * 16 + (li & 7) * 2) = f2bf(h);
        }
      }
    }
    if (it + 1 < ITERS) storeX(1);
    __syncthreads();   // B2: AT, HF ready; XF(it+1) staged

    // ---- GEMM3: S = H @ W2^T + b2 (each wave one ct3 = w) ----
    f32x4 sacc[4];
    #pragma unroll
    for (int rt = 0; rt < 4; ++rt) sacc[rt] = (f32x4){b2r, b2r, b2r, b2r};
    #pragma unroll
    for (int rt = 0; rt < 4; ++rt)
      #pragma unroll
      for (int ks = 0; ks < 2; ++ks) {
        bf16x8 ha = ldf(smem, HF_OFF + ((rt * 2 + ks) * 64 + lane) * 16);
        sacc[rt] = __builtin_amdgcn_mfma_f32_16x16x32_bf16(ha, w2b[ks], sacc[rt], 0, 0, 0);
      }
    #pragma unroll
    for (int rt = 0; rt < 4; ++rt) {
      uint2 pk; pk.x = pack2(sacc[rt][0], sacc[rt][1]); pk.y = pack2(sacc[rt][2], sacc[rt][3]);
      const int laneB = li + 16 * ((rt & 1) * 2 + (quad >> 1));
      *reinterpret_cast<uint2*>(smem + SF_OFF
          + ((w * 2 + (rt >> 1)) * 64 + laneB) * 16 + (quad & 1) * 8) = pk;
    }
    __syncthreads();   // B3: SF ready

    // ---- AGG: agg[k][d] += assign^T @ sq over 64 rows ----
    #pragma unroll
    for (int ks = 0; ks < 2; ++ks) {
      bf16x8 sf[4];
      #pragma unroll
      for (int nt = 0; nt < 4; ++nt)
        sf[nt] = ldf(smem, SF_OFF + ((nt * 2 + ks) * 64 + lane) * 16);
      #pragma unroll
      for (int m = 0; m < 2; ++m) {
        bf16x8 af = ldf(smem, AT_OFF + (((w * 2 + m) * 2 + ks) * 64 + lane) * 16);
        #pragma unroll
        for (int nt = 0; nt < 4; ++nt)
          gacc[m][nt] = __builtin_amdgcn_mfma_f32_16x16x32_bf16(af, sf[nt], gacc[m][nt], 0, 0, 0);
      }
    }
  }

  // ---- epilogue: per-block partial (mode=1) or atomic (mode=0) ----
  float* aggB = aggP + (size_t)(mode ? (b * BLKPB + blk) : b) * (K_ * DC_);
  #pragma unroll
  for (int m = 0; m < 2; ++m)
    #pragma unroll
    for (int nt = 0; nt < 4; ++nt)
      #pragma unroll
      for (int r = 0; r < 4; ++r) {
        const int o = ((w * 2 + m) * 16 + quad * 4 + r) * 64 + nt * 16 + li;
        if (mode) aggB[o] = gacc[m][nt][r];
        else atomicAdd(&aggB[o], gacc[m][nt][r]);
      }
  float* massB = massP + (size_t)(mode ? (b * BLKPB + blk) : b) * K_;
  if (w < 3) {
    #pragma unroll
    for (int j = 0; j < 3; ++j) if (j < nWa) {
      float v = massA[j];
      v += __shfl_xor(v, 16, 64);
      v += __shfl_xor(v, 32, 64);
      if (lane < 16) {
        const int k = (3 * w + j) * 16 + li;
        if (mode) massB[k] = v;
        else atomicAdd(&massB[k], v);
      }
    }
  }
}

__global__ __launch_bounds__(1024)
void netvlad_phase2(const float* __restrict__ aggP, const float* __restrict__ massP,
                    const float* __restrict__ centroid, float* __restrict__ out, int P)
{
  __shared__ float v[K_ * DC_];
  __shared__ float ms[K_];
  __shared__ float red[16];
  const int b = blockIdx.x, t = threadIdx.x;
  if (t < K_) {
    float s = 0.f;
    for (int p = 0; p < P; ++p) s += massP[(size_t)(b * P + p) * K_ + t];
    ms[t] = s;
  }
  __syncthreads();
  float ss = 0.f;
  for (int idx = t; idx < K_ * DC_; idx += 1024) {
    float s = 0.f;
    for (int p = 0; p < P; ++p) s += aggP[(size_t)(b * P + p) * (K_ * DC_) + idx];
    float val = s - ms[idx >> 6] * centroid[idx];
    v[idx] = val;
    ss += val * val;
  }
  #pragma unroll
  for (int off = 32; off > 0; off >>= 1) ss += __shfl_down(ss, off, 64);
  if ((t & 63) == 0) red[t >> 6] = ss;
  __syncthreads();
  if (t == 0) {
    float s = 0.f;
    #pragma unroll
    for (int i = 0; i < 16; ++i) s += red[i];
    red[0] = 1.0f / fmaxf(sqrtf(s), 1e-12f);
  }
  __syncthreads();
  const float inv = red[0];
  for (int idx = t; idx < K_ * DC_; idx += 1024)
    out[(size_t)b * (K_ * DC_) + idx] = v[idx] * inv;
}

extern "C" void kernel_launch(void* const* d_in, const int* in_sizes, int n_in,
                              void* d_out, int out_size, void* d_ws, size_t ws_size,
                              hipStream_t stream) {
  const float* desc     = (const float*)d_in[0];
  const float* W1       = (const float*)d_in[1];
  const float* b1       = (const float*)d_in[2];
  const float* W2       = (const float*)d_in[3];
  const float* b2       = (const float*)d_in[4];
  const float* Wa       = (const float*)d_in[5];
  const float* ba       = (const float*)d_in[6];
  const float* centroid = (const float*)d_in[7];
  float* out = (float*)d_out;

  const size_t needPartial =
      (size_t)(B_ * BLKPB) * (K_ * DC_ + K_) * sizeof(float);   // ~17 MB
  const int mode = (ws_size >= needPartial) ? 1 : 0;
  const int P = mode ? BLKPB : 1;

  float* aggP  = (float*)d_ws;
  float* massP = aggP + (size_t)(B_ * P) * (K_ * DC_);
  if (!mode) {
    size_t zbytes = (size_t)B_ * (K_ * DC_ + K_) * sizeof(float);
    hipMemsetAsync(d_ws, 0, zbytes, stream);
  }

  hipFuncSetAttribute(reinterpret_cast<const void*>(netvlad_phase1),
                      hipFuncAttributeMaxDynamicSharedMemorySize, LDS_BYTES);

  netvlad_phase1<<<dim3(B_ * BLKPB), dim3(256), LDS_BYTES, stream>>>(
      desc, W1, b1, W2, b2, Wa, ba, aggP, massP, mode);
  netvlad_phase2<<<dim3(B_), dim3(1024), 0, stream>>>(aggP, massP, centroid, out, P);
}